// Round 6
// baseline (63.233 us; speedup 1.0000x reference)
//
#include <hip/hip_runtime.h>
#include <math.h>

#define B_ 8
#define M_ 10
#define S_ 200
#define PADS_ 208            // S padded to multiple of 16 (sentinel points)
#define N_ 2048
#define L_ 128
#define BETA_ 0.01f
#define EPS_ 1e-6f
#define INF_U 0x7F7F7F7Fu
#define SENT_ 5.0e18f        // sentinel coord; |p|^2 = 7.5e37 dominates, never wins min

#define NT_ 32                          // n per dist block
#define DIST_BLOCKS (B_ * (N_ / NT_))   // 512

__device__ __forceinline__ float fexp_(float x, float p) {
    float s = (x > 0.f) ? 1.f : ((x < 0.f) ? -1.f : 0.f);
    return s * powf(fmaxf(fabsf(x), EPS_), p);
}

// ---------------------------------------------------------------------------
// Kernel 0: rotation matrices + padded surface points (w = |p|^2) + ws init
// grid: 80 blocks x 256
// ---------------------------------------------------------------------------
__global__ void prep_k(const float* __restrict__ rot, const float* __restrict__ size,
                       const float* __restrict__ shp, const float* __restrict__ def,
                       const float* __restrict__ etas, const float* __restrict__ omegas,
                       float* __restrict__ wsR, float4* __restrict__ wsPts,
                       unsigned int* __restrict__ gmin, float* __restrict__ acc)
{
    int bm = blockIdx.x;      // 0..B*M-1
    int t = threadIdx.x;
    int gid = bm * 256 + t;
    if (gid < B_*M_*S_) gmin[gid] = INF_U;
    if (gid == 0) acc[0] = 0.f;

    if (t == 0) {
        float w = rot[bm*4+0], x = rot[bm*4+1], y = rot[bm*4+2], z = rot[bm*4+3];
        float inv = 1.f / sqrtf(w*w + x*x + y*y + z*z);
        w *= inv; x *= inv; y *= inv; z *= inv;
        float* Rm = wsR + bm*9;
        Rm[0] = 1.f - 2.f*(y*y + z*z); Rm[1] = 2.f*(x*y - w*z);       Rm[2] = 2.f*(x*z + w*y);
        Rm[3] = 2.f*(x*y + w*z);       Rm[4] = 1.f - 2.f*(x*x + z*z); Rm[5] = 2.f*(y*z - w*x);
        Rm[6] = 2.f*(x*z - w*y);       Rm[7] = 2.f*(y*z + w*x);       Rm[8] = 1.f - 2.f*(x*x + y*y);
    }
    if (t < PADS_) {
        if (t < S_) {
            float a1 = size[bm*3+0], a2 = size[bm*3+1], a3 = size[bm*3+2];
            float e1 = shp[bm*2+0],  e2 = shp[bm*2+1];
            float d0 = def[bm*2+0],  d1 = def[bm*2+1];
            float eta = etas[bm*S_+t], om = omegas[bm*S_+t];
            float ce = cosf(eta), se = sinf(eta);
            float co = cosf(om),  so = sinf(om);
            float fce = fexp_(ce, e1), fse = fexp_(se, e1);
            float fco = fexp_(co, e2), fso = fexp_(so, e2);
            float px = a1 * fce * fco;
            float py = a2 * fce * fso;
            float pz = a3 * fse;
            float fr = pz / a3;
            px *= d0*fr + 1.f;
            py *= d1*fr + 1.f;
            wsPts[bm*PADS_+t] = make_float4(px, py, pz, px*px + py*py + pz*pz);
        } else {
            wsPts[bm*PADS_+t] = make_float4(SENT_, SENT_, SENT_, 3.f*SENT_*SENT_);
        }
    }
}

// ---------------------------------------------------------------------------
// Unified dist kernel: ONE pass over dist[b,m,s,n], both reductions in regs.
//   grid = 512 blocks x 256. Block = (b, 32-n tile).
//   Thread sub-tile: sg = lane&15 owns 13 s (s = k*16+sg, padded to 208);
//                    (wave, ngw=lane>>4) owns 2 n.
//   m-loop is FULLY UNROLLED: all V0/V1/sm indices compile-time -> VGPRs,
//   not scratch (rule #20 — the partial unroll was demoting them to
//   scratch; VGPR_Count 44 was the tell).
// ---------------------------------------------------------------------------
__global__ __launch_bounds__(256) void dist_k(const float* __restrict__ ipts,
                                              const float* __restrict__ trans,
                                              const float* __restrict__ probs,
                                              const float* __restrict__ wsR,
                                              const float4* __restrict__ wsPts,
                                              unsigned int* __restrict__ gmin,
                                              float* __restrict__ acc)
{
    __shared__ unsigned int sMin[M_ * PADS_];   // 8320 B
    __shared__ float sSum[4];
    int t = threadIdx.x;
    int b = blockIdx.x / (N_ / NT_);
    int tile = blockIdx.x % (N_ / NT_);
    int lane = t & 63, wave = t >> 6;
    int sg = lane & 15;          // s-group (lane bits 0..3)
    int ngw = lane >> 4;         // n-subgroup within wave (lane bits 4..5)

    for (int i = t; i < M_*PADS_; i += 256) sMin[i] = INF_U;
    __syncthreads();

    int n0 = tile*NT_ + wave*8 + ngw*2;
    const float* ip = ipts + (size_t)(b*N_ + n0)*3;
    float x0 = ip[0], y0 = ip[1], z0 = ip[2];
    float x1 = ip[3], y1 = ip[4], z1 = ip[5];

    const float*  Rb = wsR   + b*M_*9;    // block-uniform -> scalar loads
    const float*  Tb = trans + b*M_*3;
    const float4* Pb = wsPts + b*M_*PADS_;

    float V0[M_], V1[M_];

    #pragma unroll
    for (int m = 0; m < M_; ++m) {
        float r00 = Rb[m*9+0], r01 = Rb[m*9+1], r02 = Rb[m*9+2];
        float r10 = Rb[m*9+3], r11 = Rb[m*9+4], r12 = Rb[m*9+5];
        float r20 = Rb[m*9+6], r21 = Rb[m*9+7], r22 = Rb[m*9+8];
        float tx = Tb[m*3+0], ty = Tb[m*3+1], tz = Tb[m*3+2];

        float cx = x0 - tx, cy = y0 - ty, cz = z0 - tz;
        float X00 = r00*cx + r01*cy + r02*cz;
        float X01 = r10*cx + r11*cy + r12*cz;
        float X02 = r20*cx + r21*cy + r22*cz;
        float A00 = -2.f*X00, A01 = -2.f*X01, A02 = -2.f*X02;
        float c20 = X00*X00 + X01*X01 + X02*X02;

        cx = x1 - tx; cy = y1 - ty; cz = z1 - tz;
        float X10 = r00*cx + r01*cy + r02*cz;
        float X11 = r10*cx + r11*cy + r12*cz;
        float X12 = r20*cx + r21*cy + r22*cz;
        float A10 = -2.f*X10, A11 = -2.f*X11, A12 = -2.f*X12;
        float c21 = X10*X10 + X11*X11 + X12*X12;

        float vm0 = 3.4e38f, vm1 = 3.4e38f;
        float sm[13];
        const float4* Pm = Pb + m*PADS_ + sg;
        #pragma unroll
        for (int k = 0; k < 13; ++k) {
            float4 p = Pm[k*16];                 // imm-offset global loads (L1/L2)
            float w0 = p.w + c20;
            float d0 = fmaf(p.x, A00, fmaf(p.y, A01, fmaf(p.z, A02, w0)));
            float w1 = p.w + c21;
            float d1 = fmaf(p.x, A10, fmaf(p.y, A11, fmaf(p.z, A12, w1)));
            vm0 = fminf(vm0, d0);
            vm1 = fminf(vm1, d1);
            sm[k] = fminf(d0, d1);               // each (m,k) assigned exactly once
        }
        V0[m] = vm0; V1[m] = vm1;

        // smin: reduce over the 16 n-groups = lane bits 4,5 + cross-wave via LDS
        #pragma unroll
        for (int k = 0; k < 13; ++k) {
            float v = sm[k];
            v = fminf(v, __shfl_xor(v, 16));
            v = fminf(v, __shfl_xor(v, 32));
            sm[k] = v;
        }
        if (ngw == 0) {                          // lanes 0..15: one atomic per s
            #pragma unroll
            for (int k = 0; k < 13; ++k)
                atomicMin(&sMin[m*PADS_ + k*16 + sg], __float_as_uint(sm[k]));
        }
    }

    // V: min over the 16 s-groups (lane bits 0..3)
    #pragma unroll
    for (int m = 0; m < M_; ++m) {
        #pragma unroll
        for (int o = 1; o < 16; o <<= 1) {
            V0[m] = fminf(V0[m], __shfl_xor(V0[m], o));
            V1[m] = fminf(V1[m], __shfl_xor(V1[m], o));
        }
    }

    // sort + Fs weighting for both n (uniform within 16-lane group)
    float sum01 = 0.f;
    {
        float P[M_];
        #pragma unroll
        for (int m = 0; m < M_; ++m) P[m] = probs[b*M_ + m];
        #pragma unroll
        for (int i = 0; i < M_-1; ++i)
            #pragma unroll
            for (int j = 0; j < M_-1-i; ++j)
                if (V0[j] > V0[j+1]) {
                    float tv = V0[j]; V0[j] = V0[j+1]; V0[j+1] = tv;
                    float tp = P[j];  P[j]  = P[j+1];  P[j+1]  = tp;
                }
        float cum = 1.f;
        #pragma unroll
        for (int i = 0; i < M_; ++i) { sum01 += P[i] * cum * V0[i]; cum *= (1.f - P[i]); }
    }
    {
        float P[M_];
        #pragma unroll
        for (int m = 0; m < M_; ++m) P[m] = probs[b*M_ + m];
        #pragma unroll
        for (int i = 0; i < M_-1; ++i)
            #pragma unroll
            for (int j = 0; j < M_-1-i; ++j)
                if (V1[j] > V1[j+1]) {
                    float tv = V1[j]; V1[j] = V1[j+1]; V1[j+1] = tv;
                    float tp = P[j];  P[j]  = P[j+1];  P[j+1]  = tp;
                }
        float cum = 1.f;
        #pragma unroll
        for (int i = 0; i < M_; ++i) { sum01 += P[i] * cum * V1[i]; cum *= (1.f - P[i]); }
    }

    float contrib = (sg == 0) ? sum01 : 0.f;     // 4 contributing lanes per wave
    #pragma unroll
    for (int o = 1; o < 64; o <<= 1) contrib += __shfl_xor(contrib, o);
    if (lane == 0) sSum[wave] = contrib;

    __syncthreads();                             // sMin + sSum complete
    if (t == 0) atomicAdd(acc, sSum[0] + sSum[1] + sSum[2] + sSum[3]);

    // merge per-block smin into global (skip sentinel s >= 200)
    for (int i = t; i < M_*PADS_; i += 256) {
        int s = i % PADS_;
        if (s < S_) {
            int m = i / PADS_;
            atomicMin(&gmin[(b*M_ + m)*S_ + s], sMin[i]);
        }
    }
}

// ---------------------------------------------------------------------------
// Finalize: prim_to_pcl from gmin (uint4 loads), KLD, combine. 1 block x 1024.
// ---------------------------------------------------------------------------
__global__ __launch_bounds__(1024) void final_k(const unsigned int* __restrict__ gmin,
                                                const float* __restrict__ probs,
                                                const float* __restrict__ mu,
                                                const float* __restrict__ logvar,
                                                const float* __restrict__ acc,
                                                float* __restrict__ out)
{
    int t = threadIdx.x;
    const uint4* g4 = (const uint4*)gmin;    // 4000 uint4; 200%4==0 -> no bm straddle
    float s1 = 0.f;
    for (int i = t; i < (B_*M_*S_)/4; i += 1024) {
        uint4 v = g4[i];
        float p = probs[i / 50];             // bm = (4i)/200 = i/50
        s1 += p * (__uint_as_float(v.x) + __uint_as_float(v.y) +
                   __uint_as_float(v.z) + __uint_as_float(v.w));
    }
    float s2 = 0.f;
    for (int i = t; i < B_*L_; i += 1024) {
        float muv = mu[i], lv = logvar[i];
        s2 += -0.5f * (1.f + lv - muv*muv - expf(lv));
    }
    #pragma unroll
    for (int o = 1; o < 64; o <<= 1) {
        s1 += __shfl_xor(s1, o);
        s2 += __shfl_xor(s2, o);
    }
    __shared__ float r1[16], r2[16];
    int wave = t >> 6, lane = t & 63;
    if (lane == 0) { r1[wave] = s1; r2[wave] = s2; }
    __syncthreads();
    if (t == 0) {
        float S1 = 0.f, S2 = 0.f;
        #pragma unroll
        for (int w = 0; w < 16; ++w) { S1 += r1[w]; S2 += r2[w]; }
        float prim_to_pcl = S1 / (float)(B_ * S_);
        float kld = S2 / (float)B_;
        float pcl_to_prim = acc[0] / (float)(B_ * N_);
        float prims = pcl_to_prim + prim_to_pcl;
        out[0] = prims + BETA_ * kld;   // total
        out[1] = prims;
        out[2] = 0.f;                   // regs
        out[3] = kld;
    }
}

extern "C" void kernel_launch(void* const* d_in, const int* in_sizes, int n_in,
                              void* d_out, int out_size, void* d_ws, size_t ws_size,
                              hipStream_t stream) {
    const float* ipts    = (const float*)d_in[0];
    const float* trans   = (const float*)d_in[1];
    const float* rot     = (const float*)d_in[2];
    const float* size    = (const float*)d_in[3];
    const float* shp     = (const float*)d_in[4];
    const float* def     = (const float*)d_in[5];
    const float* probs   = (const float*)d_in[6];
    const float* etas    = (const float*)d_in[7];
    const float* omegas  = (const float*)d_in[8];
    const float* mu      = (const float*)d_in[9];
    const float* logvar  = (const float*)d_in[10];
    float* out = (float*)d_out;

    char* ws = (char*)d_ws;
    unsigned int* gmin = (unsigned int*)ws;          // B*M*S*4        = 64000 B
    float* acc    = (float*)(ws + 64000);            // 64 B
    float* wsR    = (float*)(ws + 64064);            // B*M*9*4        = 2880 B
    float4* wsPts = (float4*)(ws + 66944);           // B*M*PADS*16    = 266240 B

    prep_k<<<B_*M_, 256, 0, stream>>>(rot, size, shp, def, etas, omegas,
                                      wsR, wsPts, gmin, acc);
    dist_k<<<DIST_BLOCKS, 256, 0, stream>>>(ipts, trans, probs,
                                            wsR, wsPts, gmin, acc);
    final_k<<<1, 1024, 0, stream>>>(gmin, probs, mu, logvar, acc, out);
}

// Round 7
// 27.703 us; speedup vs baseline: 2.2825x; 2.2825x over previous
//
#include <hip/hip_runtime.h>
#include <math.h>

#define B_ 8
#define M_ 10
#define S_ 200
#define PADS_ 208            // S padded to multiple of 16 (sentinel points)
#define N_ 2048
#define L_ 128
#define BETA_ 0.01f
#define EPS_ 1e-6f
#define INF_U 0x7F7F7F7Fu
#define SENT_ 5.0e18f        // sentinel coord; |p|^2 = 7.5e37, finite, never wins min

#define NT_ 128                           // n per dist block
#define TILES_ (N_ / NT_)                 // 16
#define DIST_BLOCKS (B_ * M_ * TILES_)    // 1280

__device__ __forceinline__ float fexp_(float x, float p) {
    float s = (x > 0.f) ? 1.f : ((x < 0.f) ? -1.f : 0.f);
    return s * powf(fmaxf(fabsf(x), EPS_), p);
}

// ---------------------------------------------------------------------------
// Kernel 0: rotation matrices + padded surface points (w = |p|^2) + ws init
// grid: 80 blocks x 256
// ---------------------------------------------------------------------------
__global__ void prep_k(const float* __restrict__ rot, const float* __restrict__ size,
                       const float* __restrict__ shp, const float* __restrict__ def,
                       const float* __restrict__ etas, const float* __restrict__ omegas,
                       float* __restrict__ wsR, float4* __restrict__ wsPts,
                       unsigned int* __restrict__ gmin, float* __restrict__ acc)
{
    int bm = blockIdx.x;      // 0..B*M-1
    int t = threadIdx.x;
    int gid = bm * 256 + t;
    if (gid < B_*M_*S_) gmin[gid] = INF_U;
    if (gid == 0) acc[0] = 0.f;

    if (t == 0) {
        float w = rot[bm*4+0], x = rot[bm*4+1], y = rot[bm*4+2], z = rot[bm*4+3];
        float inv = 1.f / sqrtf(w*w + x*x + y*y + z*z);
        w *= inv; x *= inv; y *= inv; z *= inv;
        float* Rm = wsR + bm*9;
        Rm[0] = 1.f - 2.f*(y*y + z*z); Rm[1] = 2.f*(x*y - w*z);       Rm[2] = 2.f*(x*z + w*y);
        Rm[3] = 2.f*(x*y + w*z);       Rm[4] = 1.f - 2.f*(x*x + z*z); Rm[5] = 2.f*(y*z - w*x);
        Rm[6] = 2.f*(x*z - w*y);       Rm[7] = 2.f*(y*z + w*x);       Rm[8] = 1.f - 2.f*(x*x + y*y);
    }
    if (t < PADS_) {
        if (t < S_) {
            float a1 = size[bm*3+0], a2 = size[bm*3+1], a3 = size[bm*3+2];
            float e1 = shp[bm*2+0],  e2 = shp[bm*2+1];
            float d0 = def[bm*2+0],  d1 = def[bm*2+1];
            float eta = etas[bm*S_+t], om = omegas[bm*S_+t];
            float ce = cosf(eta), se = sinf(eta);
            float co = cosf(om),  so = sinf(om);
            float fce = fexp_(ce, e1), fse = fexp_(se, e1);
            float fco = fexp_(co, e2), fso = fexp_(so, e2);
            float px = a1 * fce * fco;
            float py = a2 * fce * fso;
            float pz = a3 * fse;
            float fr = pz / a3;
            px *= d0*fr + 1.f;
            py *= d1*fr + 1.f;
            wsPts[bm*PADS_+t] = make_float4(px, py, pz, px*px + py*py + pz*pz);
        } else {
            wsPts[bm*PADS_+t] = make_float4(SENT_, SENT_, SENT_, 3.f*SENT_*SENT_);
        }
    }
}

// ---------------------------------------------------------------------------
// dist_k: block = (b, m, 128-n tile). ONE m per block -> thread state is
// m-free (8 n-accumulators only). grid = 1280 x 256 (5 blocks/CU).
//   Stage: pts[208] (3.3KB) + rotated n-points as (A=-2X, c2=|X|^2) (2KB).
//   Thread: sg = lane&15 owns 13 s (s = k*16+sg); ng = wave*4+(lane>>4)
//           owns 8 n. Inner iter: 1 ds_read_b128 (2-way conflict = free)
//           + 8 evals (3 fma + add + min each).
//   V (min over s): shfl over lane bits 0..3 -> sV -> coalesced store to
//     vpart[b][m][n] (final value, block owns all s). No atomics.
//   smin (min over n): in-loop 2 shfl (bits 4,5) + LDS atomicMin, merged
//     to gmin once per block (200 atomics).
// ---------------------------------------------------------------------------
__global__ __launch_bounds__(256) void dist_k(const float* __restrict__ ipts,
                                              const float* __restrict__ trans,
                                              const float* __restrict__ wsR,
                                              const float4* __restrict__ wsPts,
                                              unsigned int* __restrict__ gmin,
                                              float* __restrict__ vpart)
{
    __shared__ float4 sPts[PADS_];          // 3328 B
    __shared__ float4 sXt[NT_];             // 2048 B  (A0,A1,A2,c2)
    __shared__ unsigned int sMinS[PADS_];   // 832 B
    __shared__ float sV[NT_];               // 512 B

    int t = threadIdx.x;
    int tile = blockIdx.x % TILES_;
    int bm   = blockIdx.x / TILES_;
    int b    = bm / M_;

    for (int i = t; i < PADS_; i += 256) {
        sPts[i] = wsPts[bm*PADS_ + i];
        sMinS[i] = INF_U;
    }
    if (t < NT_) {
        int n = tile*NT_ + t;
        const float* ip = ipts + (size_t)(b*N_ + n)*3;
        float cx = ip[0] - trans[bm*3+0];
        float cy = ip[1] - trans[bm*3+1];
        float cz = ip[2] - trans[bm*3+2];
        float X0 = wsR[bm*9+0]*cx + wsR[bm*9+1]*cy + wsR[bm*9+2]*cz;
        float X1 = wsR[bm*9+3]*cx + wsR[bm*9+4]*cy + wsR[bm*9+5]*cz;
        float X2 = wsR[bm*9+6]*cx + wsR[bm*9+7]*cy + wsR[bm*9+8]*cz;
        sXt[t] = make_float4(-2.f*X0, -2.f*X1, -2.f*X2, X0*X0 + X1*X1 + X2*X2);
    }
    __syncthreads();

    int lane = t & 63, wave = t >> 6;
    int sg = lane & 15;                    // s-group (lane bits 0..3)
    int ng = wave*4 + (lane >> 4);         // n-group 0..15, owns n = ng*8+j

    float4 A[8];
    #pragma unroll
    for (int j = 0; j < 8; ++j) A[j] = sXt[ng*8 + j];   // broadcast reads

    float vmin[8];
    #pragma unroll
    for (int j = 0; j < 8; ++j) vmin[j] = 3.4e38f;

    #pragma unroll 4
    for (int k = 0; k < 13; ++k) {
        float4 p = sPts[k*16 + sg];        // 16 consecutive float4 = free 2-way
        float dm = 3.4e38f;
        #pragma unroll
        for (int j = 0; j < 8; ++j) {
            float d = fmaf(p.x, A[j].x,
                      fmaf(p.y, A[j].y,
                      fmaf(p.z, A[j].z, p.w + A[j].w)));
            vmin[j] = fminf(vmin[j], d);
            dm = fminf(dm, d);
        }
        // min over the 16 n-groups: lane bits 4,5 in-wave, waves via LDS atomic
        dm = fminf(dm, __shfl_xor(dm, 16));
        dm = fminf(dm, __shfl_xor(dm, 32));
        if (lane < 16) atomicMin(&sMinS[k*16 + sg], __float_as_uint(dm));
    }

    // V: min over the 16 s-groups (lane bits 0..3)
    #pragma unroll
    for (int j = 0; j < 8; ++j) {
        float v = vmin[j];
        #pragma unroll
        for (int o = 1; o < 16; o <<= 1) v = fminf(v, __shfl_xor(v, o));
        vmin[j] = v;
    }
    if (sg == 0) {
        #pragma unroll
        for (int j = 0; j < 8; ++j) sV[ng*8 + j] = vmin[j];
    }
    __syncthreads();

    if (t < NT_) vpart[bm*N_ + tile*NT_ + t] = sV[t];        // coalesced, final
    if (t < S_)  atomicMin(&gmin[bm*S_ + t], sMinS[t]);      // 200 atomics/block
}

// ---------------------------------------------------------------------------
// vsort_k: per point n, read V[b][:, n] (coalesced), sort M=10, Fs weighting,
// reduce -> acc. grid = B*N/256 = 64 blocks.
// ---------------------------------------------------------------------------
__global__ __launch_bounds__(256) void vsort_k(const float* __restrict__ vpart,
                                               const float* __restrict__ probs,
                                               float* __restrict__ acc)
{
    int t = threadIdx.x;
    int g = blockIdx.x*256 + t;            // 0..B*N-1
    int b = g / N_, n = g % N_;

    float V[M_], P[M_];
    #pragma unroll
    for (int m = 0; m < M_; ++m) {
        V[m] = vpart[(b*M_ + m)*N_ + n];   // coalesced per m
        P[m] = probs[b*M_ + m];
    }
    #pragma unroll
    for (int i = 0; i < M_-1; ++i)
        #pragma unroll
        for (int j = 0; j < M_-1-i; ++j)
            if (V[j] > V[j+1]) {
                float tv = V[j]; V[j] = V[j+1]; V[j+1] = tv;
                float tp = P[j]; P[j] = P[j+1]; P[j+1] = tp;
            }
    float cum = 1.f, sum = 0.f;
    #pragma unroll
    for (int i = 0; i < M_; ++i) { sum += P[i] * cum * V[i]; cum *= (1.f - P[i]); }

    #pragma unroll
    for (int o = 1; o < 64; o <<= 1) sum += __shfl_xor(sum, o);
    __shared__ float sSum[4];
    int wave = t >> 6, lane = t & 63;
    if (lane == 0) sSum[wave] = sum;
    __syncthreads();
    if (t == 0) atomicAdd(acc, sSum[0] + sSum[1] + sSum[2] + sSum[3]);
}

// ---------------------------------------------------------------------------
// Finalize: prim_to_pcl from gmin (uint4 loads), KLD, combine. 1 block x 1024.
// ---------------------------------------------------------------------------
__global__ __launch_bounds__(1024) void final_k(const unsigned int* __restrict__ gmin,
                                                const float* __restrict__ probs,
                                                const float* __restrict__ mu,
                                                const float* __restrict__ logvar,
                                                const float* __restrict__ acc,
                                                float* __restrict__ out)
{
    int t = threadIdx.x;
    const uint4* g4 = (const uint4*)gmin;    // 4000 uint4; 200%4==0 -> no bm straddle
    float s1 = 0.f;
    for (int i = t; i < (B_*M_*S_)/4; i += 1024) {
        uint4 v = g4[i];
        float p = probs[i / 50];             // bm = (4i)/200 = i/50
        s1 += p * (__uint_as_float(v.x) + __uint_as_float(v.y) +
                   __uint_as_float(v.z) + __uint_as_float(v.w));
    }
    float s2 = 0.f;
    for (int i = t; i < B_*L_; i += 1024) {
        float muv = mu[i], lv = logvar[i];
        s2 += -0.5f * (1.f + lv - muv*muv - expf(lv));
    }
    #pragma unroll
    for (int o = 1; o < 64; o <<= 1) {
        s1 += __shfl_xor(s1, o);
        s2 += __shfl_xor(s2, o);
    }
    __shared__ float r1[16], r2[16];
    int wave = t >> 6, lane = t & 63;
    if (lane == 0) { r1[wave] = s1; r2[wave] = s2; }
    __syncthreads();
    if (t == 0) {
        float S1 = 0.f, S2 = 0.f;
        #pragma unroll
        for (int w = 0; w < 16; ++w) { S1 += r1[w]; S2 += r2[w]; }
        float prim_to_pcl = S1 / (float)(B_ * S_);
        float kld = S2 / (float)B_;
        float pcl_to_prim = acc[0] / (float)(B_ * N_);
        float prims = pcl_to_prim + prim_to_pcl;
        out[0] = prims + BETA_ * kld;   // total
        out[1] = prims;
        out[2] = 0.f;                   // regs
        out[3] = kld;
    }
}

extern "C" void kernel_launch(void* const* d_in, const int* in_sizes, int n_in,
                              void* d_out, int out_size, void* d_ws, size_t ws_size,
                              hipStream_t stream) {
    const float* ipts    = (const float*)d_in[0];
    const float* trans   = (const float*)d_in[1];
    const float* rot     = (const float*)d_in[2];
    const float* size    = (const float*)d_in[3];
    const float* shp     = (const float*)d_in[4];
    const float* def     = (const float*)d_in[5];
    const float* probs   = (const float*)d_in[6];
    const float* etas    = (const float*)d_in[7];
    const float* omegas  = (const float*)d_in[8];
    const float* mu      = (const float*)d_in[9];
    const float* logvar  = (const float*)d_in[10];
    float* out = (float*)d_out;

    char* ws = (char*)d_ws;
    unsigned int* gmin = (unsigned int*)ws;          // B*M*S*4        = 64000 B
    float* acc    = (float*)(ws + 64000);            // 64 B
    float* wsR    = (float*)(ws + 64064);            // B*M*9*4        = 2880 B
    float4* wsPts = (float4*)(ws + 66944);           // B*M*PADS*16    = 266240 B
    float* vpart  = (float*)(ws + 333184);           // B*M*N*4        = 655360 B

    prep_k<<<B_*M_, 256, 0, stream>>>(rot, size, shp, def, etas, omegas,
                                      wsR, wsPts, gmin, acc);
    dist_k<<<DIST_BLOCKS, 256, 0, stream>>>(ipts, trans, wsR, wsPts, gmin, vpart);
    vsort_k<<<(B_*N_)/256, 256, 0, stream>>>(vpart, probs, acc);
    final_k<<<1, 1024, 0, stream>>>(gmin, probs, mu, logvar, acc, out);
}